// Round 4
// baseline (255.517 us; speedup 1.0000x reference)
//
#include <hip/hip_runtime.h>
#include <cstdint>

#define BB 4
#define SEQ 2048
#define EMB 768
#define NH 8
#define HD 96
#define E3 2304
#define MTOK 8192
#define SCALING 0.10206207261596575f
#define LOG2E 1.44269504f

typedef unsigned short u16;
typedef unsigned int u32;
typedef __bf16 bf16x8 __attribute__((ext_vector_type(8)));
typedef float f32x4 __attribute__((ext_vector_type(4)));
typedef float f32x16 __attribute__((ext_vector_type(16)));

__device__ __forceinline__ u16 f2bf(float f) {
    union { float f; uint32_t u; } c; c.f = f;
    uint32_t u = c.u;
    return (u16)((u + 0x7FFFu + ((u >> 16) & 1u)) >> 16);
}
__device__ __forceinline__ u16 f2bf_fast(float f) {
    union { float f; uint32_t u; } c; c.f = f;
    return (u16)((c.u + 0x8000u) >> 16);
}
__device__ __forceinline__ uint32_t pk2(float a, float b) {
    return (uint32_t)f2bf(a) | ((uint32_t)f2bf(b) << 16);
}
__device__ __forceinline__ uint32_t pk2_fast(float a, float b) {
    return (uint32_t)f2bf_fast(a) | ((uint32_t)f2bf_fast(b) << 16);
}
__device__ __forceinline__ float fexp2(float x) {
    return __builtin_amdgcn_exp2f(x);
}
// async global->LDS, 16B per lane. LDS dest = uniform base + lane*16.
__device__ __forceinline__ void async16(const u16* g, u16* l) {
    __builtin_amdgcn_global_load_lds(
        (const __attribute__((address_space(1))) void*)g,
        (__attribute__((address_space(3))) void*)l, 16, 0, 0);
}

// ---------------- converts ----------------

__global__ void cvt_x_kernel(const float* __restrict__ src, u16* __restrict__ dst, int n8) {
    int i = blockIdx.x * blockDim.x + threadIdx.x;
    if (i >= n8) return;
    const float4* s4 = (const float4*)src;
    float4 a = s4[2 * i];
    float4 c = s4[2 * i + 1];
    uint4 o;
    o.x = pk2(a.x, a.y); o.y = pk2(a.z, a.w);
    o.z = pk2(c.x, c.y); o.w = pk2(c.z, c.w);
    ((uint4*)dst)[i] = o;
}

// dst[j][k] = src[k][c(j)], bf16.
// mode 0: c=j (Wproj). mode 1: QK cols j<1536: c=(rr/96)*288+(rr%96)*3+s, s=j/768.
// mode 2: V rows j<768: c=(j/96)*288+(j%96)*3+2.
__global__ __launch_bounds__(256) void transpose_w_kernel(const float* __restrict__ src,
                                                          u16* __restrict__ dst,
                                                          int ncols, int mode) {
    __shared__ float T[64][65];
    int j0 = blockIdx.x * 64, k0 = blockIdx.y * 64;
    int tid = threadIdx.x;
#pragma unroll
    for (int it = 0; it < 16; ++it) {
        int lin = it * 256 + tid;
        int rr2 = lin >> 6, jj = lin & 63;
        int j = j0 + jj;
        int c;
        if (mode == 0) c = j;
        else if (mode == 1) { int s = j / 768, rr = j % 768; c = (rr / 96) * 288 + (rr % 96) * 3 + s; }
        else { c = (j / 96) * 288 + (j % 96) * 3 + 2; }
        T[rr2][jj] = src[(k0 + rr2) * ncols + c];
    }
    __syncthreads();
#pragma unroll
    for (int it = 0; it < 16; ++it) {
        int lin = it * 256 + tid;
        int jr = lin >> 6, kc = lin & 63;
        dst[(size_t)(j0 + jr) * 768 + k0 + kc] = f2bf(T[kc][jr]);
    }
}

// ---------------- NT-GEMM mainloop (m97 structure): global_load_lds + XOR-swizzled LDS --

__device__ __forceinline__ void gemm_tiles(const u16* __restrict__ A,
                                           const u16* __restrict__ Bt,
                                           int m0, int n0, int tid,
                                           u16* As, u16* Bs, f32x4 acc[4][4]) {
    const int lane = tid & 63;
    const int w = tid >> 6;
    const int l15 = lane & 15;
    const int quad = lane >> 4;
    const int wr = (w >> 1) * 64;
    const int wc = (w & 1) * 64;
    const int swz = l15 & 7;
    for (int kb = 0; kb < 768; kb += 64) {
#pragma unroll
        for (int it = 0; it < 4; ++it) {
            int base = (w * 4 + it) * 64;
            int lin = base + lane;
            int row = lin >> 3, cl = lin & 7;
            int cg = cl ^ (row & 7);
            async16(&A[(size_t)(m0 + row) * 768 + kb + cg * 8], &As[base * 8]);
            async16(&Bt[(size_t)(n0 + row) * 768 + kb + cg * 8], &Bs[base * 8]);
        }
        __syncthreads();
#pragma unroll
        for (int ks = 0; ks < 2; ++ks) {
            bf16x8 af[4], bfg[4];
#pragma unroll
            for (int fi = 0; fi < 4; ++fi)
                af[fi] = *(const bf16x8*)&As[(wr + fi * 16 + l15) * 64 + (((ks * 4 + quad) ^ swz) * 8)];
#pragma unroll
            for (int fj = 0; fj < 4; ++fj)
                bfg[fj] = *(const bf16x8*)&Bs[(wc + fj * 16 + l15) * 64 + (((ks * 4 + quad) ^ swz) * 8)];
#pragma unroll
            for (int fi = 0; fi < 4; ++fi)
#pragma unroll
                for (int fj = 0; fj < 4; ++fj)
                    acc[fi][fj] = __builtin_amdgcn_mfma_f32_16x16x32_bf16(af[fi], bfg[fj], acc[fi][fj], 0, 0, 0);
        }
        __syncthreads();
    }
}

// Q/K projection: M=8192 tokens x N=1536 cols. Q pre-scaled by LOG2E -> qb[bh][n][96].
// K -> kg[bh][n][128], chunk-swizzled: cp = (dd>>3) ^ (n&7). Bias permute inline.
__global__ __launch_bounds__(256) void gemm_qk_kernel(const u16* __restrict__ A,
                                                      const u16* __restrict__ Bt,
                                                      const float* __restrict__ bqkv,
                                                      u16* __restrict__ qb,
                                                      u16* __restrict__ kg) {
    __shared__ __align__(16) u16 As[128 * 64];
    __shared__ __align__(16) u16 Bs[128 * 64];
    int tid = threadIdx.x;
    int n0 = blockIdx.x * 128, m0 = blockIdx.y * 128;
    f32x4 acc[4][4] = {};
    gemm_tiles(A, Bt, m0, n0, tid, As, Bs, acc);
    int lane = tid & 63, w = tid >> 6, l15 = lane & 15, quad = lane >> 4;
    int wr = (w >> 1) * 64, wc = (w & 1) * 64;
#pragma unroll
    for (int fj = 0; fj < 4; ++fj) {
        int j = n0 + wc + fj * 16 + l15;
        int s = j / 768, rr = j % 768;
        int hh = rr / 96, dd = rr % 96;
        float bv = bqkv[hh * 288 + dd * 3 + s];
#pragma unroll
        for (int fi = 0; fi < 4; ++fi) {
#pragma unroll
            for (int r = 0; r < 4; ++r) {
                int m = m0 + wr + fi * 16 + quad * 4 + r;
                int b = m >> 11, n = m & 2047;
                int bh = b * NH + hh;
                float v = acc[fi][fj][r] + bv;
                if (s == 0) {
                    qb[((size_t)bh * SEQ + n) * HD + dd] = f2bf(v * LOG2E);
                } else {
                    int cp = (dd >> 3) ^ (n & 7);
                    kg[((size_t)bh * SEQ + n) * 128 + cp * 8 + (dd & 7)] = f2bf(v);
                }
            }
        }
    }
}

// V projection, transposed: C[dd_global][token] = Wv_rows . xb^T (NT: A=wvr, Bt=xb).
// Epilogue: coalesced stores into vt[bh][dd][2048] with per-64-token chunk swizzle.
__global__ __launch_bounds__(256) void gemm_v_kernel(const u16* __restrict__ A,
                                                     const u16* __restrict__ Bt,
                                                     const float* __restrict__ bqkv,
                                                     u16* __restrict__ vt) {
    __shared__ __align__(16) u16 As[128 * 64];
    __shared__ __align__(16) u16 Bs[128 * 64];
    int tid = threadIdx.x;
    int n0 = blockIdx.x * 128, m0 = blockIdx.y * 128;
    f32x4 acc[4][4] = {};
    gemm_tiles(A, Bt, m0, n0, tid, As, Bs, acc);
    int lane = tid & 63, w = tid >> 6, l15 = lane & 15, quad = lane >> 4;
    int wr = (w >> 1) * 64, wc = (w & 1) * 64;
    float bvs[4][4]; int hhs[4][4], dds[4][4];
#pragma unroll
    for (int fi = 0; fi < 4; ++fi)
#pragma unroll
        for (int r = 0; r < 4; ++r) {
            int m = m0 + wr + fi * 16 + quad * 4 + r;
            int hh = m / 96, dd = m % 96;
            hhs[fi][r] = hh; dds[fi][r] = dd;
            bvs[fi][r] = bqkv[hh * 288 + dd * 3 + 2];
        }
#pragma unroll
    for (int fj = 0; fj < 4; ++fj) {
        int n = n0 + wc + fj * 16 + l15;
        int b = n >> 11, nn = n & 2047;
#pragma unroll
        for (int fi = 0; fi < 4; ++fi) {
#pragma unroll
            for (int r = 0; r < 4; ++r) {
                int dd = dds[fi][r];
                int kk = (nn & ~63) | ((((nn >> 3) ^ dd) & 7) << 3) | (nn & 7);
                vt[((size_t)(b * NH + hhs[fi][r]) * HD + dd) * SEQ + kk] =
                    f2bf(acc[fi][fj][r] + bvs[fi][r]);
            }
        }
    }
}

__global__ __launch_bounds__(256) void gemm_proj_kernel(const u16* __restrict__ A,
                                                        const u16* __restrict__ Bt,
                                                        const float* __restrict__ bias,
                                                        float* __restrict__ out) {
    __shared__ __align__(16) u16 As[128 * 64];
    __shared__ __align__(16) u16 Bs[128 * 64];
    int tid = threadIdx.x;
    int n0 = blockIdx.x * 128, m0 = blockIdx.y * 128;
    f32x4 acc[4][4] = {};
    gemm_tiles(A, Bt, m0, n0, tid, As, Bs, acc);
    int lane = tid & 63, w = tid >> 6, l15 = lane & 15, quad = lane >> 4;
    int wr = (w >> 1) * 64, wc = (w & 1) * 64;
#pragma unroll
    for (int fj = 0; fj < 4; ++fj) {
        int j = n0 + wc + fj * 16 + l15;
        float bv = bias[j];
#pragma unroll
        for (int fi = 0; fi < 4; ++fi) {
#pragma unroll
            for (int r = 0; r < 4; ++r) {
                int m = m0 + wr + fi * 16 + quad * 4 + r;
                out[(size_t)m * 768 + j] = acc[fi][fj][r] + bv;
            }
        }
    }
}

// ---------------- flash attention, 32x32x16 MFMA, transposed scores, double-buffered ----
// 4 waves x 32 q-rows (BQ=128). S' = K.Q^T so P' is keys-on-rows / q-on-cols; PV
// B-operand built in registers via one half-wave shuffle per packed pair. K/V staged by
// global_load_lds; next tile prefetched BEFORE computing current (one barrier/iter).
__global__ __launch_bounds__(256) void attn_kernel(const u16* __restrict__ Q,
                                                   const u16* __restrict__ Kg,
                                                   const u16* __restrict__ Vt,
                                                   u16* __restrict__ AO) {
    __shared__ __align__(16) u16 Ks[2][64 * 128];   // 32 KB
    __shared__ __align__(16) u16 Vs[2][96 * 64];    // 24 KB
    int tid = threadIdx.x;
    int lane = tid & 63, w = tid >> 6;
    int l31 = lane & 31, hf = lane >> 5;
    int swz = l31 & 7;
    int qt = blockIdx.x, bh = blockIdx.y;
    int b = bh >> 3, head = bh & 7;
    const u16* qp = Q + (size_t)bh * SEQ * HD;
    const u16* kgp = Kg + (size_t)bh * SEQ * 128;
    const u16* vtp = Vt + (size_t)bh * HD * SEQ;
    int q0 = qt * 128 + w * 32;

    // Q B-operand frags in registers for the whole kernel
    bf16x8 aq[6];
#pragma unroll
    for (int dc = 0; dc < 6; ++dc)
        aq[dc] = *(const bf16x8*)&qp[(size_t)(q0 + l31) * HD + dc * 16 + hf * 8];

    f32x16 Ot[3] = {};
    float lp = 0.f;

    auto stage = [&](int kt, int buf) {
        int k0 = kt * 64;
#pragma unroll
        for (int it = 0; it < 4; ++it) {
            int cw = w * 4 + it;
            async16(kgp + (size_t)(k0 + cw * 4 + (lane >> 4)) * 128 + (lane & 15) * 8,
                    &Ks[buf][cw * 512]);
        }
#pragma unroll
        for (int it = 0; it < 3; ++it) {
            int vw = w * 3 + it;
            async16(vtp + (size_t)(vw * 8 + (lane >> 3)) * SEQ + k0 + (lane & 7) * 8,
                    &Vs[buf][vw * 512]);
        }
    };

    stage(0, 0);
    __syncthreads();

    for (int kt = 0; kt < SEQ / 64; ++kt) {
        int cur = kt & 1;
        if (kt + 1 < SEQ / 64) stage(kt + 1, cur ^ 1);   // prefetch overlaps compute

        // S' = K . Q^T : rows key, cols q
        f32x16 Sv[2] = {};
#pragma unroll
        for (int tau = 0; tau < 2; ++tau) {
#pragma unroll
            for (int dc = 0; dc < 6; ++dc) {
                bf16x8 ka = *(const bf16x8*)&Ks[cur][(tau * 32 + l31) * 128 + (((2 * dc + hf) ^ swz) * 8)];
                Sv[tau] = __builtin_amdgcn_mfma_f32_32x32x16_bf16(ka, aq[dc], Sv[tau], 0, 0, 0);
            }
        }

        // P' = 2^S' (Q pre-scaled by log2e); pack key-pairs; accumulate row sums
        u32 pk[2][4][2];
#pragma unroll
        for (int tau = 0; tau < 2; ++tau)
#pragma unroll
            for (int g = 0; g < 4; ++g)
#pragma unroll
                for (int u = 0; u < 2; ++u) {
                    float p0 = fexp2(Sv[tau][g * 4 + 2 * u]);
                    float p1 = fexp2(Sv[tau][g * 4 + 2 * u + 1]);
                    lp += p0 + p1;
                    pk[tau][g][u] = pk2_fast(p0, p1);
                }
        // half-wave exchange to build P^T B-operand frags
        u32 rv[2][2][2];
#pragma unroll
        for (int tau = 0; tau < 2; ++tau)
#pragma unroll
            for (int kc = 0; kc < 2; ++kc)
#pragma unroll
                for (int u = 0; u < 2; ++u) {
                    u32 send = hf ? pk[tau][2 * kc][u] : pk[tau][2 * kc + 1][u];
                    rv[tau][kc][u] = (u32)__shfl_xor((int)send, 32);
                }
        // PV: O^T += V^T . P'
#pragma unroll
        for (int tau = 0; tau < 2; ++tau) {
#pragma unroll
            for (int kc = 0; kc < 2; ++kc) {
                union { u32 u[4]; bf16x8 v; } pf;
                pf.u[0] = hf ? rv[tau][kc][0] : pk[tau][2 * kc][0];
                pf.u[1] = hf ? rv[tau][kc][1] : pk[tau][2 * kc][1];
                pf.u[2] = hf ? pk[tau][2 * kc + 1][0] : rv[tau][kc][0];
                pf.u[3] = hf ? pk[tau][2 * kc + 1][1] : rv[tau][kc][1];
#pragma unroll
                for (int t = 0; t < 3; ++t) {
                    bf16x8 va = *(const bf16x8*)&Vs[cur][(t * 32 + l31) * 64 + (((4 * tau + 2 * kc + hf) ^ swz) * 8)];
                    Ot[t] = __builtin_amdgcn_mfma_f32_32x32x16_bf16(va, pf.v, Ot[t], 0, 0, 0);
                }
            }
        }
        __syncthreads();   // waits prefetch (vmcnt) + all waves done with buf `cur`
    }

    // epilogue: one half-wave reduce for l, then scale + packed 8B stores
    float l = lp + __shfl_xor(lp, 32);
    float sc = SCALING / l;
    int n = q0 + l31;
    size_t rowbase = ((size_t)b * SEQ + n) * EMB + head * HD;
#pragma unroll
    for (int t = 0; t < 3; ++t) {
#pragma unroll
        for (int g = 0; g < 4; ++g) {
            int d0 = t * 32 + 8 * g + 4 * hf;
            uint2 val;
            val.x = pk2(Ot[t][g * 4 + 0] * sc, Ot[t][g * 4 + 1] * sc);
            val.y = pk2(Ot[t][g * 4 + 2] * sc, Ot[t][g * 4 + 3] * sc);
            *(uint2*)&AO[rowbase + d0] = val;
        }
    }
}

// ---------------- launch ----------------

extern "C" void kernel_launch(void* const* d_in, const int* in_sizes, int n_in,
                              void* d_out, int out_size, void* d_ws, size_t ws_size,
                              hipStream_t stream) {
    const float* x     = (const float*)d_in[0];
    const float* Wqkv  = (const float*)d_in[1];
    const float* bqkv  = (const float*)d_in[2];
    const float* Wproj = (const float*)d_in[3];
    const float* bproj = (const float*)d_in[4];
    float* out = (float*)d_out;

    char* p = (char*)d_ws;
    u16*   xb   = (u16*)p;  p += (size_t)MTOK * EMB * 2;
    u16*   wqkT = (u16*)p;  p += (size_t)1536 * EMB * 2;
    u16*   wvr  = (u16*)p;  p += (size_t)EMB * EMB * 2;
    u16*   wpt  = (u16*)p;  p += (size_t)EMB * EMB * 2;
    u16*   qb   = (u16*)p;  p += (size_t)MTOK * EMB * 2;
    u16*   kg   = (u16*)p;  p += (size_t)BB * NH * SEQ * 128 * 2;
    u16*   vt   = (u16*)p;  p += (size_t)MTOK * EMB * 2;
    u16*   ao   = (u16*)p;  p += (size_t)MTOK * EMB * 2;

    cvt_x_kernel<<<MTOK * EMB / 8 / 256, 256, 0, stream>>>(x, xb, MTOK * EMB / 8);
    transpose_w_kernel<<<dim3(1536 / 64, EMB / 64), 256, 0, stream>>>(Wqkv, wqkT, E3, 1);
    transpose_w_kernel<<<dim3(EMB / 64, EMB / 64), 256, 0, stream>>>(Wqkv, wvr, E3, 2);
    transpose_w_kernel<<<dim3(EMB / 64, EMB / 64), 256, 0, stream>>>(Wproj, wpt, EMB, 0);
    gemm_qk_kernel<<<dim3(1536 / 128, MTOK / 128), 256, 0, stream>>>(xb, wqkT, bqkv, qb, kg);
    gemm_v_kernel<<<dim3(MTOK / 128, EMB / 128), 256, 0, stream>>>(wvr, xb, bqkv, vt);
    attn_kernel<<<dim3(SEQ / 128, BB * NH), 256, 0, stream>>>(qb, kg, vt, ao);
    gemm_proj_kernel<<<dim3(EMB / 128, MTOK / 128), 256, 0, stream>>>(ao, wpt, bproj, out);
}

// Round 5
// 251.073 us; speedup vs baseline: 1.0177x; 1.0177x over previous
//
#include <hip/hip_runtime.h>
#include <cstdint>

#define BB 4
#define SEQ 2048
#define EMB 768
#define NH 8
#define HD 96
#define E3 2304
#define MTOK 8192
#define NROWS 65536            // BB*NH*SEQ
#define SCALING 0.10206207261596575f
#define LOG2E 1.44269504f

typedef unsigned short u16;
typedef unsigned int u32;
typedef __bf16 bf16x8 __attribute__((ext_vector_type(8)));
typedef float f32x4 __attribute__((ext_vector_type(4)));
typedef float f32x16 __attribute__((ext_vector_type(16)));

__device__ __forceinline__ u16 f2bf(float f) {
    union { float f; uint32_t u; } c; c.f = f;
    uint32_t u = c.u;
    return (u16)((u + 0x7FFFu + ((u >> 16) & 1u)) >> 16);
}
__device__ __forceinline__ u16 f2bf_fast(float f) {
    union { float f; uint32_t u; } c; c.f = f;
    return (u16)((c.u + 0x8000u) >> 16);
}
__device__ __forceinline__ uint32_t pk2(float a, float b) {
    return (uint32_t)f2bf(a) | ((uint32_t)f2bf(b) << 16);
}
__device__ __forceinline__ uint32_t pk2_fast(float a, float b) {
    return (uint32_t)f2bf_fast(a) | ((uint32_t)f2bf_fast(b) << 16);
}
__device__ __forceinline__ float bf2f(u16 h) {
    union { uint32_t u; float f; } c; c.u = ((uint32_t)h) << 16; return c.f;
}
__device__ __forceinline__ float fexp2(float x) {
    return __builtin_amdgcn_exp2f(x);
}
__device__ __forceinline__ void async16(const u16* g, u16* l) {
    __builtin_amdgcn_global_load_lds(
        (const __attribute__((address_space(1))) void*)g,
        (__attribute__((address_space(3))) void*)l, 16, 0, 0);
}

// ---------------- converts ----------------

__global__ void cvt_x_kernel(const float* __restrict__ src, u16* __restrict__ dst, int n8) {
    int i = blockIdx.x * blockDim.x + threadIdx.x;
    if (i >= n8) return;
    const float4* s4 = (const float4*)src;
    float4 a = s4[2 * i];
    float4 c = s4[2 * i + 1];
    uint4 o;
    o.x = pk2(a.x, a.y); o.y = pk2(a.z, a.w);
    o.z = pk2(c.x, c.y); o.w = pk2(c.z, c.w);
    ((uint4*)dst)[i] = o;
}

// dst[j][k] = src[k][c(j)], bf16.
// mode 0: c=j (Wproj). mode 1: QK cols j<1536. mode 2: V rows j<768.
__global__ __launch_bounds__(256) void transpose_w_kernel(const float* __restrict__ src,
                                                          u16* __restrict__ dst,
                                                          int ncols, int mode) {
    __shared__ float T[64][65];
    int j0 = blockIdx.x * 64, k0 = blockIdx.y * 64;
    int tid = threadIdx.x;
#pragma unroll
    for (int it = 0; it < 16; ++it) {
        int lin = it * 256 + tid;
        int rr2 = lin >> 6, jj = lin & 63;
        int j = j0 + jj;
        int c;
        if (mode == 0) c = j;
        else if (mode == 1) { int s = j / 768, rr = j % 768; c = (rr / 96) * 288 + (rr % 96) * 3 + s; }
        else { c = (j / 96) * 288 + (j % 96) * 3 + 2; }
        T[rr2][jj] = src[(k0 + rr2) * ncols + c];
    }
    __syncthreads();
#pragma unroll
    for (int it = 0; it < 16; ++it) {
        int lin = it * 256 + tid;
        int jr = lin >> 6, kc = lin & 63;
        dst[(size_t)(j0 + jr) * 768 + k0 + kc] = f2bf(T[kc][jr]);
    }
}

// ---------------- NT-GEMM mainloops: global_load_lds + XOR-swizzled LDS ----------------

// 128x128 tile
__device__ __forceinline__ void gemm_tiles(const u16* __restrict__ A,
                                           const u16* __restrict__ Bt,
                                           int m0, int n0, int tid,
                                           u16* As, u16* Bs, f32x4 acc[4][4]) {
    const int lane = tid & 63;
    const int w = tid >> 6;
    const int l15 = lane & 15;
    const int quad = lane >> 4;
    const int wr = (w >> 1) * 64;
    const int wc = (w & 1) * 64;
    const int swz = l15 & 7;
    for (int kb = 0; kb < 768; kb += 64) {
#pragma unroll
        for (int it = 0; it < 4; ++it) {
            int base = (w * 4 + it) * 64;
            int lin = base + lane;
            int row = lin >> 3, cl = lin & 7;
            int cg = cl ^ (row & 7);
            async16(&A[(size_t)(m0 + row) * 768 + kb + cg * 8], &As[base * 8]);
            async16(&Bt[(size_t)(n0 + row) * 768 + kb + cg * 8], &Bs[base * 8]);
        }
        __syncthreads();
#pragma unroll
        for (int ks = 0; ks < 2; ++ks) {
            bf16x8 af[4], bfg[4];
#pragma unroll
            for (int fi = 0; fi < 4; ++fi)
                af[fi] = *(const bf16x8*)&As[(wr + fi * 16 + l15) * 64 + (((ks * 4 + quad) ^ swz) * 8)];
#pragma unroll
            for (int fj = 0; fj < 4; ++fj)
                bfg[fj] = *(const bf16x8*)&Bs[(wc + fj * 16 + l15) * 64 + (((ks * 4 + quad) ^ swz) * 8)];
#pragma unroll
            for (int fi = 0; fi < 4; ++fi)
#pragma unroll
                for (int fj = 0; fj < 4; ++fj)
                    acc[fi][fj] = __builtin_amdgcn_mfma_f32_16x16x32_bf16(af[fi], bfg[fj], acc[fi][fj], 0, 0, 0);
        }
        __syncthreads();
    }
}

// 128x64 tile (for skinny-N GEMMs: grid 768 = 3 blocks/CU even)
__device__ __forceinline__ void gemm_tiles64(const u16* __restrict__ A,
                                             const u16* __restrict__ Bt,
                                             int m0, int n0, int tid,
                                             u16* As, u16* Bs, f32x4 acc[4][2]) {
    const int lane = tid & 63;
    const int w = tid >> 6;
    const int l15 = lane & 15;
    const int quad = lane >> 4;
    const int wr = (w >> 1) * 64;
    const int wc = (w & 1) * 32;
    const int swz = l15 & 7;
    for (int kb = 0; kb < 768; kb += 64) {
#pragma unroll
        for (int it = 0; it < 4; ++it) {
            int base = (w * 4 + it) * 64;
            int lin = base + lane;
            int row = lin >> 3, cl = lin & 7;
            int cg = cl ^ (row & 7);
            async16(&A[(size_t)(m0 + row) * 768 + kb + cg * 8], &As[base * 8]);
        }
#pragma unroll
        for (int it = 0; it < 2; ++it) {
            int base = (w * 2 + it) * 64;
            int lin = base + lane;
            int row = lin >> 3, cl = lin & 7;
            int cg = cl ^ (row & 7);
            async16(&Bt[(size_t)(n0 + row) * 768 + kb + cg * 8], &Bs[base * 8]);
        }
        __syncthreads();
#pragma unroll
        for (int ks = 0; ks < 2; ++ks) {
            bf16x8 af[4], bfg[2];
#pragma unroll
            for (int fi = 0; fi < 4; ++fi)
                af[fi] = *(const bf16x8*)&As[(wr + fi * 16 + l15) * 64 + (((ks * 4 + quad) ^ swz) * 8)];
#pragma unroll
            for (int fj = 0; fj < 2; ++fj)
                bfg[fj] = *(const bf16x8*)&Bs[(wc + fj * 16 + l15) * 64 + (((ks * 4 + quad) ^ swz) * 8)];
#pragma unroll
            for (int fi = 0; fi < 4; ++fi)
#pragma unroll
                for (int fj = 0; fj < 2; ++fj)
                    acc[fi][fj] = __builtin_amdgcn_mfma_f32_16x16x32_bf16(af[fi], bfg[fj], acc[fi][fj], 0, 0, 0);
        }
        __syncthreads();
    }
}

// Q/K projection: M=8192 x N=1536. Q pre-scaled by LOG2E -> qb[bh][n][96].
// K -> kg[bh][n][128], chunk-swizzled. Bias permute inline.
__global__ __launch_bounds__(256) void gemm_qk_kernel(const u16* __restrict__ A,
                                                      const u16* __restrict__ Bt,
                                                      const float* __restrict__ bqkv,
                                                      u16* __restrict__ qb,
                                                      u16* __restrict__ kg) {
    __shared__ __align__(16) u16 As[128 * 64];
    __shared__ __align__(16) u16 Bs[128 * 64];
    int tid = threadIdx.x;
    int n0 = blockIdx.x * 128, m0 = blockIdx.y * 128;
    f32x4 acc[4][4] = {};
    gemm_tiles(A, Bt, m0, n0, tid, As, Bs, acc);
    int lane = tid & 63, w = tid >> 6, l15 = lane & 15, quad = lane >> 4;
    int wr = (w >> 1) * 64, wc = (w & 1) * 64;
#pragma unroll
    for (int fj = 0; fj < 4; ++fj) {
        int j = n0 + wc + fj * 16 + l15;
        int s = j / 768, rr = j % 768;
        int hh = rr / 96, dd = rr % 96;
        float bv = bqkv[hh * 288 + dd * 3 + s];
#pragma unroll
        for (int fi = 0; fi < 4; ++fi) {
#pragma unroll
            for (int r = 0; r < 4; ++r) {
                int m = m0 + wr + fi * 16 + quad * 4 + r;
                int b = m >> 11, n = m & 2047;
                int bh = b * NH + hh;
                float v = acc[fi][fj][r] + bv;
                if (s == 0) {
                    qb[((size_t)bh * SEQ + n) * HD + dd] = f2bf(v * LOG2E);
                } else {
                    int cp = (dd >> 3) ^ (n & 7);
                    kg[((size_t)bh * SEQ + n) * 128 + cp * 8 + (dd & 7)] = f2bf(v);
                }
            }
        }
    }
}

// V projection, transposed: C[dd_global][token] = Wv_rows . xb^T. 128(M)x64(N) tiles.
__global__ __launch_bounds__(256) void gemm_v_kernel(const u16* __restrict__ A,
                                                     const u16* __restrict__ Bt,
                                                     const float* __restrict__ bqkv,
                                                     u16* __restrict__ vt) {
    __shared__ __align__(16) u16 As[128 * 64];
    __shared__ __align__(16) u16 Bs[64 * 64];
    int tid = threadIdx.x;
    int n0 = blockIdx.x * 64, m0 = blockIdx.y * 128;
    f32x4 acc[4][2] = {};
    gemm_tiles64(A, Bt, m0, n0, tid, As, Bs, acc);
    int lane = tid & 63, w = tid >> 6, l15 = lane & 15, quad = lane >> 4;
    int wr = (w >> 1) * 64, wc = (w & 1) * 32;
    float bvs[4][4]; int hhs[4][4], dds[4][4];
#pragma unroll
    for (int fi = 0; fi < 4; ++fi)
#pragma unroll
        for (int r = 0; r < 4; ++r) {
            int m = m0 + wr + fi * 16 + quad * 4 + r;
            int hh = m / 96, dd = m % 96;
            hhs[fi][r] = hh; dds[fi][r] = dd;
            bvs[fi][r] = bqkv[hh * 288 + dd * 3 + 2];
        }
#pragma unroll
    for (int fj = 0; fj < 2; ++fj) {
        int n = n0 + wc + fj * 16 + l15;
        int b = n >> 11, nn = n & 2047;
#pragma unroll
        for (int fi = 0; fi < 4; ++fi) {
#pragma unroll
            for (int r = 0; r < 4; ++r) {
                int dd = dds[fi][r];
                int kk = (nn & ~63) | ((((nn >> 3) ^ dd) & 7) << 3) | (nn & 7);
                vt[((size_t)(b * NH + hhs[fi][r]) * HD + dd) * SEQ + kk] =
                    f2bf(acc[fi][fj][r] + bvs[fi][r]);
            }
        }
    }
}

// out projection: 128(M)x64(N) tiles, grid 12x64 = 768 = 3/CU even.
__global__ __launch_bounds__(256) void gemm_proj_kernel(const u16* __restrict__ A,
                                                        const u16* __restrict__ Bt,
                                                        const float* __restrict__ bias,
                                                        float* __restrict__ out) {
    __shared__ __align__(16) u16 As[128 * 64];
    __shared__ __align__(16) u16 Bs[64 * 64];
    int tid = threadIdx.x;
    int n0 = blockIdx.x * 64, m0 = blockIdx.y * 128;
    f32x4 acc[4][2] = {};
    gemm_tiles64(A, Bt, m0, n0, tid, As, Bs, acc);
    int lane = tid & 63, w = tid >> 6, l15 = lane & 15, quad = lane >> 4;
    int wr = (w >> 1) * 64, wc = (w & 1) * 32;
#pragma unroll
    for (int fj = 0; fj < 2; ++fj) {
        int j = n0 + wc + fj * 16 + l15;
        float bv = bias[j];
#pragma unroll
        for (int fi = 0; fi < 4; ++fi) {
#pragma unroll
            for (int r = 0; r < 4; ++r) {
                int m = m0 + wr + fi * 16 + quad * 4 + r;
                out[(size_t)m * 768 + j] = acc[fi][fj][r] + bv;
            }
        }
    }
}

// ---------------- flash attention: 2 q-tiles/wave, 2-way K-split ----------------
// Block: 4 waves x 64 q (BQ=256), keys [kh*1024, +1024) in 16 tiles of 64.
// Each K-frag / V-frag LDS read feeds TWO MFMAs (one per q-tile) -> LDS:MFMA = 1:2.
// No-max softmax => K-split combine is a pure sum of partial O^T (bf16) and l (f32).
__global__ __launch_bounds__(256, 2) void attn_kernel(const u16* __restrict__ Q,
                                                      const u16* __restrict__ Kg,
                                                      const u16* __restrict__ Vt,
                                                      u16* __restrict__ part,
                                                      float* __restrict__ lpart) {
    __shared__ __align__(16) u16 Ks[2][64 * 128];   // 32 KB
    __shared__ __align__(16) u16 Vs[2][96 * 64];    // 24 KB
    int tid = threadIdx.x;
    int lane = tid & 63, w = tid >> 6;
    int l31 = lane & 31, hf = lane >> 5;
    int swz = l31 & 7;
    int qt = blockIdx.x, bh = blockIdx.y, kh = blockIdx.z;
    const u16* qp = Q + (size_t)bh * SEQ * HD;
    const u16* kgp = Kg + (size_t)bh * SEQ * 128;
    const u16* vtp = Vt + (size_t)bh * HD * SEQ;
    int qbase = qt * 256 + w * 64;
    int kbase = kh * 1024;

    // Q B-operand frags: 2 q-tiles x 6 d-chunks, in registers for whole kernel
    bf16x8 aq[2][6];
#pragma unroll
    for (int j = 0; j < 2; ++j)
#pragma unroll
        for (int dc = 0; dc < 6; ++dc)
            aq[j][dc] = *(const bf16x8*)&qp[(size_t)(qbase + j * 32 + l31) * HD + dc * 16 + hf * 8];

    f32x16 Ot[2][3] = {};
    float lp[2] = {0.f, 0.f};

    auto stage = [&](int kt, int buf) {
        int k0 = kbase + kt * 64;
#pragma unroll
        for (int it = 0; it < 4; ++it) {
            int cw = w * 4 + it;
            async16(kgp + (size_t)(k0 + cw * 4 + (lane >> 4)) * 128 + (lane & 15) * 8,
                    &Ks[buf][cw * 512]);
        }
#pragma unroll
        for (int it = 0; it < 3; ++it) {
            int vw = w * 3 + it;
            async16(vtp + (size_t)(vw * 8 + (lane >> 3)) * SEQ + k0 + (lane & 7) * 8,
                    &Vs[buf][vw * 512]);
        }
    };

    stage(0, 0);
    __syncthreads();

    for (int kt = 0; kt < 16; ++kt) {
        int cur = kt & 1;
        if (kt + 1 < 16) stage(kt + 1, cur ^ 1);

        // per 32-key group tau: S' -> softmax -> shuffle -> PV (keeps Sv live-range small)
#pragma unroll
        for (int tau = 0; tau < 2; ++tau) {
            f32x16 Sv0 = {}, Sv1 = {};
#pragma unroll
            for (int dc = 0; dc < 6; ++dc) {
                bf16x8 ka = *(const bf16x8*)&Ks[cur][(tau * 32 + l31) * 128 + (((2 * dc + hf) ^ swz) * 8)];
                Sv0 = __builtin_amdgcn_mfma_f32_32x32x16_bf16(ka, aq[0][dc], Sv0, 0, 0, 0);
                Sv1 = __builtin_amdgcn_mfma_f32_32x32x16_bf16(ka, aq[1][dc], Sv1, 0, 0, 0);
            }
            // P' = 2^S' (Q pre-scaled by log2e); pack key-pairs; accumulate row sums
            u32 pk[2][4][2];
#pragma unroll
            for (int g = 0; g < 4; ++g)
#pragma unroll
                for (int u = 0; u < 2; ++u) {
                    float a0 = fexp2(Sv0[g * 4 + 2 * u]);
                    float a1 = fexp2(Sv0[g * 4 + 2 * u + 1]);
                    lp[0] += a0 + a1;
                    pk[0][g][u] = pk2_fast(a0, a1);
                    float b0 = fexp2(Sv1[g * 4 + 2 * u]);
                    float b1 = fexp2(Sv1[g * 4 + 2 * u + 1]);
                    lp[1] += b0 + b1;
                    pk[1][g][u] = pk2_fast(b0, b1);
                }
            // half-wave exchange -> P^T B-operand frags
            u32 rv[2][2][2];
#pragma unroll
            for (int j = 0; j < 2; ++j)
#pragma unroll
                for (int kc = 0; kc < 2; ++kc)
#pragma unroll
                    for (int u = 0; u < 2; ++u) {
                        u32 send = hf ? pk[j][2 * kc][u] : pk[j][2 * kc + 1][u];
                        rv[j][kc][u] = (u32)__shfl_xor((int)send, 32);
                    }
            // PV: each va read feeds both q-tiles
#pragma unroll
            for (int kc = 0; kc < 2; ++kc) {
                union { u32 u[4]; bf16x8 v; } pf0, pf1;
                pf0.u[0] = hf ? rv[0][kc][0] : pk[0][2 * kc][0];
                pf0.u[1] = hf ? rv[0][kc][1] : pk[0][2 * kc][1];
                pf0.u[2] = hf ? pk[0][2 * kc + 1][0] : rv[0][kc][0];
                pf0.u[3] = hf ? pk[0][2 * kc + 1][1] : rv[0][kc][1];
                pf1.u[0] = hf ? rv[1][kc][0] : pk[1][2 * kc][0];
                pf1.u[1] = hf ? rv[1][kc][1] : pk[1][2 * kc][1];
                pf1.u[2] = hf ? pk[1][2 * kc + 1][0] : rv[1][kc][0];
                pf1.u[3] = hf ? pk[1][2 * kc + 1][1] : rv[1][kc][1];
#pragma unroll
                for (int t = 0; t < 3; ++t) {
                    bf16x8 va = *(const bf16x8*)&Vs[cur][(t * 32 + l31) * 64 + (((4 * tau + 2 * kc + hf) ^ swz) * 8)];
                    Ot[0][t] = __builtin_amdgcn_mfma_f32_32x32x16_bf16(va, pf0.v, Ot[0][t], 0, 0, 0);
                    Ot[1][t] = __builtin_amdgcn_mfma_f32_32x32x16_bf16(va, pf1.v, Ot[1][t], 0, 0, 0);
                }
            }
        }
        __syncthreads();
    }

    // epilogue: bf16 partial O^T + f32 partial l
    size_t pb = (size_t)kh * NROWS + (size_t)bh * SEQ;
#pragma unroll
    for (int j = 0; j < 2; ++j) {
        int q = qbase + j * 32 + l31;
        float lr = lp[j] + __shfl_xor(lp[j], 32);
        if (hf == 0) lpart[(size_t)kh * NROWS + (size_t)bh * SEQ + q] = lr;
        size_t rowb = (pb + q) * HD;
#pragma unroll
        for (int t = 0; t < 3; ++t) {
#pragma unroll
            for (int g = 0; g < 4; ++g) {
                int d0 = t * 32 + 8 * g + 4 * hf;
                uint2 val;
                val.x = pk2(Ot[j][t][g * 4 + 0], Ot[j][t][g * 4 + 1]);
                val.y = pk2(Ot[j][t][g * 4 + 2], Ot[j][t][g * 4 + 3]);
                *(uint2*)&part[rowb + d0] = val;
            }
        }
    }
}

// combine: ao[b][n][h*96+d] = (part0 + part1) * SCALING / (l0 + l1)
__global__ __launch_bounds__(256) void combine_kernel(const u16* __restrict__ part,
                                                      const float* __restrict__ lpart,
                                                      u16* __restrict__ ao) {
    int idx = blockIdx.x * 256 + threadIdx.x;       // NROWS*12 threads
    int row = idx / 12, ch = idx % 12;
    float l = lpart[row] + lpart[NROWS + row];
    float sc = SCALING / l;
    const uint4 p0 = *(const uint4*)&part[(size_t)row * HD + ch * 8];
    const uint4 p1 = *(const uint4*)&part[((size_t)NROWS + row) * HD + ch * 8];
    const u16* a = (const u16*)&p0;
    const u16* bq = (const u16*)&p1;
    uint4 o;
    u32* ou = (u32*)&o;
#pragma unroll
    for (int i = 0; i < 4; ++i) {
        float e0 = (bf2f(a[2 * i]) + bf2f(bq[2 * i])) * sc;
        float e1 = (bf2f(a[2 * i + 1]) + bf2f(bq[2 * i + 1])) * sc;
        ou[i] = pk2(e0, e1);
    }
    int bh = row >> 11, n = row & 2047;
    int b = bh >> 3, h = bh & 7;
    *(uint4*)&ao[((size_t)(b * SEQ + n)) * EMB + h * HD + ch * 8] = o;
}

// ---------------- launch ----------------

extern "C" void kernel_launch(void* const* d_in, const int* in_sizes, int n_in,
                              void* d_out, int out_size, void* d_ws, size_t ws_size,
                              hipStream_t stream) {
    const float* x     = (const float*)d_in[0];
    const float* Wqkv  = (const float*)d_in[1];
    const float* bqkv  = (const float*)d_in[2];
    const float* Wproj = (const float*)d_in[3];
    const float* bproj = (const float*)d_in[4];
    float* out = (float*)d_out;

    char* p = (char*)d_ws;
    u16*   xb    = (u16*)p;  p += (size_t)MTOK * EMB * 2;
    u16*   wqkT  = (u16*)p;  p += (size_t)1536 * EMB * 2;
    u16*   wvr   = (u16*)p;  p += (size_t)EMB * EMB * 2;
    u16*   wpt   = (u16*)p;  p += (size_t)EMB * EMB * 2;
    u16*   qb    = (u16*)p;  p += (size_t)MTOK * EMB * 2;
    u16*   kg    = (u16*)p;  p += (size_t)BB * NH * SEQ * 128 * 2;
    u16*   vt    = (u16*)p;  p += (size_t)MTOK * EMB * 2;
    u16*   ao    = (u16*)p;  p += (size_t)MTOK * EMB * 2;
    u16*   partb = (u16*)p;  p += (size_t)2 * NROWS * HD * 2;
    float* lpart = (float*)p; p += (size_t)2 * NROWS * 4;

    cvt_x_kernel<<<MTOK * EMB / 8 / 256, 256, 0, stream>>>(x, xb, MTOK * EMB / 8);
    transpose_w_kernel<<<dim3(1536 / 64, EMB / 64), 256, 0, stream>>>(Wqkv, wqkT, E3, 1);
    transpose_w_kernel<<<dim3(EMB / 64, EMB / 64), 256, 0, stream>>>(Wqkv, wvr, E3, 2);
    transpose_w_kernel<<<dim3(EMB / 64, EMB / 64), 256, 0, stream>>>(Wproj, wpt, EMB, 0);
    gemm_qk_kernel<<<dim3(1536 / 128, MTOK / 128), 256, 0, stream>>>(xb, wqkT, bqkv, qb, kg);
    gemm_v_kernel<<<dim3(MTOK / 64, EMB / 128), 256, 0, stream>>>(wvr, xb, bqkv, vt);
    attn_kernel<<<dim3(SEQ / 256, BB * NH, 2), 256, 0, stream>>>(qb, kg, vt, partb, lpart);
    combine_kernel<<<NROWS * 12 / 256, 256, 0, stream>>>(partb, lpart, ao);
    gemm_proj_kernel<<<dim3(EMB / 64, MTOK / 128), 256, 0, stream>>>(ao, wpt, bproj, out);
}

// Round 6
// 244.783 us; speedup vs baseline: 1.0438x; 1.0257x over previous
//
#include <hip/hip_runtime.h>
#include <cstdint>

#define BB 4
#define SEQ 2048
#define EMB 768
#define NH 8
#define HD 96
#define E3 2304
#define MTOK 8192
#define NROWS 65536            // BB*NH*SEQ
#define KSPLIT 4
#define SCALING 0.10206207261596575f
#define LOG2E 1.44269504f

typedef unsigned short u16;
typedef unsigned int u32;
typedef __bf16 bf16x8 __attribute__((ext_vector_type(8)));
typedef float f32x4 __attribute__((ext_vector_type(4)));
typedef float f32x16 __attribute__((ext_vector_type(16)));

__device__ __forceinline__ u16 f2bf(float f) {
    union { float f; uint32_t u; } c; c.f = f;
    uint32_t u = c.u;
    return (u16)((u + 0x7FFFu + ((u >> 16) & 1u)) >> 16);
}
__device__ __forceinline__ u16 f2bf_fast(float f) {
    union { float f; uint32_t u; } c; c.f = f;
    return (u16)((c.u + 0x8000u) >> 16);
}
__device__ __forceinline__ uint32_t pk2(float a, float b) {
    return (uint32_t)f2bf(a) | ((uint32_t)f2bf(b) << 16);
}
__device__ __forceinline__ uint32_t pk2_fast(float a, float b) {
    return (uint32_t)f2bf_fast(a) | ((uint32_t)f2bf_fast(b) << 16);
}
__device__ __forceinline__ float bf2f(u16 h) {
    union { uint32_t u; float f; } c; c.u = ((uint32_t)h) << 16; return c.f;
}
__device__ __forceinline__ float fexp2(float x) {
    return __builtin_amdgcn_exp2f(x);
}
__device__ __forceinline__ void async16(const u16* g, u16* l) {
    __builtin_amdgcn_global_load_lds(
        (const __attribute__((address_space(1))) void*)g,
        (__attribute__((address_space(3))) void*)l, 16, 0, 0);
}

// ---------------- fused prep: cvt_x + 3 weight transposes, one launch ----------------

__device__ __forceinline__ void transpose_body(const float* __restrict__ src,
                                               u16* __restrict__ dst,
                                               int ncols, int mode, int j0, int k0,
                                               int tid, float (*T)[65]) {
#pragma unroll
    for (int it = 0; it < 16; ++it) {
        int lin = it * 256 + tid;
        int rr2 = lin >> 6, jj = lin & 63;
        int j = j0 + jj;
        int c;
        if (mode == 0) c = j;
        else if (mode == 1) { int s = j / 768, rr = j % 768; c = (rr / 96) * 288 + (rr % 96) * 3 + s; }
        else { c = (j / 96) * 288 + (j % 96) * 3 + 2; }
        T[rr2][jj] = src[(k0 + rr2) * ncols + c];
    }
    __syncthreads();
#pragma unroll
    for (int it = 0; it < 16; ++it) {
        int lin = it * 256 + tid;
        int jr = lin >> 6, kc = lin & 63;
        dst[(size_t)(j0 + jr) * 768 + k0 + kc] = f2bf(T[kc][jr]);
    }
}

__global__ __launch_bounds__(256) void prep_kernel(const float* __restrict__ x,
                                                   const float* __restrict__ Wqkv,
                                                   const float* __restrict__ Wproj,
                                                   u16* __restrict__ xb,
                                                   u16* __restrict__ wqkT,
                                                   u16* __restrict__ wvr,
                                                   u16* __restrict__ wpt) {
    __shared__ float T[64][65];
    int bid = blockIdx.x, tid = threadIdx.x;
    if (bid < 3072) {
        int i = bid * 256 + tid;                    // 786432 chunks of 8 floats
        const float4* s4 = (const float4*)x;
        float4 a = s4[2 * i];
        float4 c = s4[2 * i + 1];
        uint4 o;
        o.x = pk2(a.x, a.y); o.y = pk2(a.z, a.w);
        o.z = pk2(c.x, c.y); o.w = pk2(c.z, c.w);
        ((uint4*)xb)[i] = o;
    } else if (bid < 3360) {
        int t = bid - 3072;
        transpose_body(Wqkv, wqkT, E3, 1, (t % 24) * 64, (t / 24) * 64, tid, T);
    } else if (bid < 3504) {
        int t = bid - 3360;
        transpose_body(Wqkv, wvr, E3, 2, (t % 12) * 64, (t / 12) * 64, tid, T);
    } else {
        int t = bid - 3504;
        transpose_body(Wproj, wpt, EMB, 0, (t % 12) * 64, (t / 12) * 64, tid, T);
    }
}

// ---------------- NT-GEMM mainloops: global_load_lds + XOR-swizzled LDS ----------------

// 128x128 tile
__device__ __forceinline__ void gemm_tiles(const u16* __restrict__ A,
                                           const u16* __restrict__ Bt,
                                           int m0, int n0, int tid,
                                           u16* As, u16* Bs, f32x4 acc[4][4]) {
    const int lane = tid & 63;
    const int w = tid >> 6;
    const int l15 = lane & 15;
    const int quad = lane >> 4;
    const int wr = (w >> 1) * 64;
    const int wc = (w & 1) * 64;
    const int swz = l15 & 7;
    for (int kb = 0; kb < 768; kb += 64) {
#pragma unroll
        for (int it = 0; it < 4; ++it) {
            int base = (w * 4 + it) * 64;
            int lin = base + lane;
            int row = lin >> 3, cl = lin & 7;
            int cg = cl ^ (row & 7);
            async16(&A[(size_t)(m0 + row) * 768 + kb + cg * 8], &As[base * 8]);
            async16(&Bt[(size_t)(n0 + row) * 768 + kb + cg * 8], &Bs[base * 8]);
        }
        __syncthreads();
#pragma unroll
        for (int ks = 0; ks < 2; ++ks) {
            bf16x8 af[4], bfg[4];
#pragma unroll
            for (int fi = 0; fi < 4; ++fi)
                af[fi] = *(const bf16x8*)&As[(wr + fi * 16 + l15) * 64 + (((ks * 4 + quad) ^ swz) * 8)];
#pragma unroll
            for (int fj = 0; fj < 4; ++fj)
                bfg[fj] = *(const bf16x8*)&Bs[(wc + fj * 16 + l15) * 64 + (((ks * 4 + quad) ^ swz) * 8)];
#pragma unroll
            for (int fi = 0; fi < 4; ++fi)
#pragma unroll
                for (int fj = 0; fj < 4; ++fj)
                    acc[fi][fj] = __builtin_amdgcn_mfma_f32_16x16x32_bf16(af[fi], bfg[fj], acc[fi][fj], 0, 0, 0);
        }
        __syncthreads();
    }
}

// 128x64 tile (skinny-N GEMMs: grid 768 = 3 blocks/CU even)
__device__ __forceinline__ void gemm_tiles64(const u16* __restrict__ A,
                                             const u16* __restrict__ Bt,
                                             int m0, int n0, int tid,
                                             u16* As, u16* Bs, f32x4 acc[4][2]) {
    const int lane = tid & 63;
    const int w = tid >> 6;
    const int l15 = lane & 15;
    const int quad = lane >> 4;
    const int wr = (w >> 1) * 64;
    const int wc = (w & 1) * 32;
    const int swz = l15 & 7;
    for (int kb = 0; kb < 768; kb += 64) {
#pragma unroll
        for (int it = 0; it < 4; ++it) {
            int base = (w * 4 + it) * 64;
            int lin = base + lane;
            int row = lin >> 3, cl = lin & 7;
            int cg = cl ^ (row & 7);
            async16(&A[(size_t)(m0 + row) * 768 + kb + cg * 8], &As[base * 8]);
        }
#pragma unroll
        for (int it = 0; it < 2; ++it) {
            int base = (w * 2 + it) * 64;
            int lin = base + lane;
            int row = lin >> 3, cl = lin & 7;
            int cg = cl ^ (row & 7);
            async16(&Bt[(size_t)(n0 + row) * 768 + kb + cg * 8], &Bs[base * 8]);
        }
        __syncthreads();
#pragma unroll
        for (int ks = 0; ks < 2; ++ks) {
            bf16x8 af[4], bfg[2];
#pragma unroll
            for (int fi = 0; fi < 4; ++fi)
                af[fi] = *(const bf16x8*)&As[(wr + fi * 16 + l15) * 64 + (((ks * 4 + quad) ^ swz) * 8)];
#pragma unroll
            for (int fj = 0; fj < 2; ++fj)
                bfg[fj] = *(const bf16x8*)&Bs[(wc + fj * 16 + l15) * 64 + (((ks * 4 + quad) ^ swz) * 8)];
#pragma unroll
            for (int fi = 0; fi < 4; ++fi)
#pragma unroll
                for (int fj = 0; fj < 2; ++fj)
                    acc[fi][fj] = __builtin_amdgcn_mfma_f32_16x16x32_bf16(af[fi], bfg[fj], acc[fi][fj], 0, 0, 0);
        }
        __syncthreads();
    }
}

// Q/K projection: M=8192 x N=1536. Q pre-scaled by LOG2E -> qb[bh][n][96].
// K -> kg[bh][n][128], chunk-swizzled. Bias permute inline.
__global__ __launch_bounds__(256) void gemm_qk_kernel(const u16* __restrict__ A,
                                                      const u16* __restrict__ Bt,
                                                      const float* __restrict__ bqkv,
                                                      u16* __restrict__ qb,
                                                      u16* __restrict__ kg) {
    __shared__ __align__(16) u16 As[128 * 64];
    __shared__ __align__(16) u16 Bs[128 * 64];
    int tid = threadIdx.x;
    int n0 = blockIdx.x * 128, m0 = blockIdx.y * 128;
    f32x4 acc[4][4] = {};
    gemm_tiles(A, Bt, m0, n0, tid, As, Bs, acc);
    int lane = tid & 63, w = tid >> 6, l15 = lane & 15, quad = lane >> 4;
    int wr = (w >> 1) * 64, wc = (w & 1) * 64;
#pragma unroll
    for (int fj = 0; fj < 4; ++fj) {
        int j = n0 + wc + fj * 16 + l15;
        int s = j / 768, rr = j % 768;
        int hh = rr / 96, dd = rr % 96;
        float bv = bqkv[hh * 288 + dd * 3 + s];
#pragma unroll
        for (int fi = 0; fi < 4; ++fi) {
#pragma unroll
            for (int r = 0; r < 4; ++r) {
                int m = m0 + wr + fi * 16 + quad * 4 + r;
                int b = m >> 11, n = m & 2047;
                int bh = b * NH + hh;
                float v = acc[fi][fj][r] + bv;
                if (s == 0) {
                    qb[((size_t)bh * SEQ + n) * HD + dd] = f2bf(v * LOG2E);
                } else {
                    int cp = (dd >> 3) ^ (n & 7);
                    kg[((size_t)bh * SEQ + n) * 128 + cp * 8 + (dd & 7)] = f2bf(v);
                }
            }
        }
    }
}

// V projection, transposed: C[dd_global][token] = Wv_rows . xb^T. 128(M)x64(N) tiles.
__global__ __launch_bounds__(256) void gemm_v_kernel(const u16* __restrict__ A,
                                                     const u16* __restrict__ Bt,
                                                     const float* __restrict__ bqkv,
                                                     u16* __restrict__ vt) {
    __shared__ __align__(16) u16 As[128 * 64];
    __shared__ __align__(16) u16 Bs[64 * 64];
    int tid = threadIdx.x;
    int n0 = blockIdx.x * 64, m0 = blockIdx.y * 128;
    f32x4 acc[4][2] = {};
    gemm_tiles64(A, Bt, m0, n0, tid, As, Bs, acc);
    int lane = tid & 63, w = tid >> 6, l15 = lane & 15, quad = lane >> 4;
    int wr = (w >> 1) * 64, wc = (w & 1) * 32;
    float bvs[4][4]; int hhs[4][4], dds[4][4];
#pragma unroll
    for (int fi = 0; fi < 4; ++fi)
#pragma unroll
        for (int r = 0; r < 4; ++r) {
            int m = m0 + wr + fi * 16 + quad * 4 + r;
            int hh = m / 96, dd = m % 96;
            hhs[fi][r] = hh; dds[fi][r] = dd;
            bvs[fi][r] = bqkv[hh * 288 + dd * 3 + 2];
        }
#pragma unroll
    for (int fj = 0; fj < 2; ++fj) {
        int n = n0 + wc + fj * 16 + l15;
        int b = n >> 11, nn = n & 2047;
#pragma unroll
        for (int fi = 0; fi < 4; ++fi) {
#pragma unroll
            for (int r = 0; r < 4; ++r) {
                int dd = dds[fi][r];
                int kk = (nn & ~63) | ((((nn >> 3) ^ dd) & 7) << 3) | (nn & 7);
                vt[((size_t)(b * NH + hhs[fi][r]) * HD + dd) * SEQ + kk] =
                    f2bf(acc[fi][fj][r] + bvs[fi][r]);
            }
        }
    }
}

// out projection: 128(M)x64(N) tiles, grid 12x64 = 768 = 3/CU even.
__global__ __launch_bounds__(256) void gemm_proj_kernel(const u16* __restrict__ A,
                                                        const u16* __restrict__ Bt,
                                                        const float* __restrict__ bias,
                                                        float* __restrict__ out) {
    __shared__ __align__(16) u16 As[128 * 64];
    __shared__ __align__(16) u16 Bs[64 * 64];
    int tid = threadIdx.x;
    int n0 = blockIdx.x * 64, m0 = blockIdx.y * 128;
    f32x4 acc[4][2] = {};
    gemm_tiles64(A, Bt, m0, n0, tid, As, Bs, acc);
    int lane = tid & 63, w = tid >> 6, l15 = lane & 15, quad = lane >> 4;
    int wr = (w >> 1) * 64, wc = (w & 1) * 32;
#pragma unroll
    for (int fj = 0; fj < 2; ++fj) {
        int j = n0 + wc + fj * 16 + l15;
        float bv = bias[j];
#pragma unroll
        for (int fi = 0; fi < 4; ++fi) {
#pragma unroll
            for (int r = 0; r < 4; ++r) {
                int m = m0 + wr + fi * 16 + quad * 4 + r;
                out[(size_t)m * 768 + j] = acc[fi][fj][r] + bv;
            }
        }
    }
}

// ---------------- flash attention: 2 q-tiles/wave, 4-way K-split, XCD-pinned ----------
// Block: 4 waves x 64 q (BQ=256); keys [kh*512, +512) in 8 tiles of 64. Single-buffered
// LDS (28.5 KB). Grid linearized as idx = qt*128 + bh*4 + kh so the 8 qt-blocks sharing
// a (bh,kh) K/V slice have equal idx%8 -> same XCD; per-XCD K/V working set
// = 16 slices x 229 KB = 3.7 MB, fits the 4 MB L2 -> K/V re-reads become L2 hits.
__global__ __launch_bounds__(256, 2) void attn_kernel(const u16* __restrict__ Q,
                                                      const u16* __restrict__ Kg,
                                                      const u16* __restrict__ Vt,
                                                      u16* __restrict__ part,
                                                      float* __restrict__ lpart) {
    __shared__ __align__(16) u16 Ks[64 * 128];   // 16 KB
    __shared__ __align__(16) u16 Vs[96 * 64];    // 12 KB
    int tid = threadIdx.x;
    int lane = tid & 63, w = tid >> 6;
    int l31 = lane & 31, hf = lane >> 5;
    int swz = l31 & 7;
    int bid = blockIdx.x;
    int qt = bid >> 7;                 // 0..7
    int g = bid & 127;
    int bh = g >> 2, kh = g & 3;       // (bh,kh) fixed -> idx%8 fixed -> same XCD
    const u16* qp = Q + (size_t)bh * SEQ * HD;
    const u16* kgp = Kg + (size_t)bh * SEQ * 128;
    const u16* vtp = Vt + (size_t)bh * HD * SEQ;
    int qbase = qt * 256 + w * 64;
    int kbase = kh * 512;

    // Q B-operand frags: 2 q-tiles x 6 d-chunks, in registers for whole kernel
    bf16x8 aq[2][6];
#pragma unroll
    for (int j = 0; j < 2; ++j)
#pragma unroll
        for (int dc = 0; dc < 6; ++dc)
            aq[j][dc] = *(const bf16x8*)&qp[(size_t)(qbase + j * 32 + l31) * HD + dc * 16 + hf * 8];

    f32x16 Ot[2][3] = {};
    float lp[2] = {0.f, 0.f};

    for (int kt = 0; kt < 8; ++kt) {
        int k0 = kbase + kt * 64;
#pragma unroll
        for (int it = 0; it < 4; ++it) {
            int cw = w * 4 + it;
            async16(kgp + (size_t)(k0 + cw * 4 + (lane >> 4)) * 128 + (lane & 15) * 8,
                    &Ks[cw * 512]);
        }
#pragma unroll
        for (int it = 0; it < 3; ++it) {
            int vw = w * 3 + it;
            async16(vtp + (size_t)(vw * 8 + (lane >> 3)) * SEQ + k0 + (lane & 7) * 8,
                    &Vs[vw * 512]);
        }
        __syncthreads();

        // per 32-key group tau: S' -> exp -> shuffle -> PV
#pragma unroll
        for (int tau = 0; tau < 2; ++tau) {
            f32x16 Sv0 = {}, Sv1 = {};
#pragma unroll
            for (int dc = 0; dc < 6; ++dc) {
                bf16x8 ka = *(const bf16x8*)&Ks[(tau * 32 + l31) * 128 + (((2 * dc + hf) ^ swz) * 8)];
                Sv0 = __builtin_amdgcn_mfma_f32_32x32x16_bf16(ka, aq[0][dc], Sv0, 0, 0, 0);
                Sv1 = __builtin_amdgcn_mfma_f32_32x32x16_bf16(ka, aq[1][dc], Sv1, 0, 0, 0);
            }
            u32 pk[2][4][2];
#pragma unroll
            for (int g2 = 0; g2 < 4; ++g2)
#pragma unroll
                for (int u = 0; u < 2; ++u) {
                    float a0 = fexp2(Sv0[g2 * 4 + 2 * u]);
                    float a1 = fexp2(Sv0[g2 * 4 + 2 * u + 1]);
                    lp[0] += a0 + a1;
                    pk[0][g2][u] = pk2_fast(a0, a1);
                    float b0 = fexp2(Sv1[g2 * 4 + 2 * u]);
                    float b1 = fexp2(Sv1[g2 * 4 + 2 * u + 1]);
                    lp[1] += b0 + b1;
                    pk[1][g2][u] = pk2_fast(b0, b1);
                }
            u32 rv[2][2][2];
#pragma unroll
            for (int j = 0; j < 2; ++j)
#pragma unroll
                for (int kc = 0; kc < 2; ++kc)
#pragma unroll
                    for (int u = 0; u < 2; ++u) {
                        u32 send = hf ? pk[j][2 * kc][u] : pk[j][2 * kc + 1][u];
                        rv[j][kc][u] = (u32)__shfl_xor((int)send, 32);
                    }
#pragma unroll
            for (int kc = 0; kc < 2; ++kc) {
                union { u32 u[4]; bf16x8 v; } pf0, pf1;
                pf0.u[0] = hf ? rv[0][kc][0] : pk[0][2 * kc][0];
                pf0.u[1] = hf ? rv[0][kc][1] : pk[0][2 * kc][1];
                pf0.u[2] = hf ? pk[0][2 * kc + 1][0] : rv[0][kc][0];
                pf0.u[3] = hf ? pk[0][2 * kc + 1][1] : rv[0][kc][1];
                pf1.u[0] = hf ? rv[1][kc][0] : pk[1][2 * kc][0];
                pf1.u[1] = hf ? rv[1][kc][1] : pk[1][2 * kc][1];
                pf1.u[2] = hf ? pk[1][2 * kc + 1][0] : rv[1][kc][0];
                pf1.u[3] = hf ? pk[1][2 * kc + 1][1] : rv[1][kc][1];
#pragma unroll
                for (int t = 0; t < 3; ++t) {
                    bf16x8 va = *(const bf16x8*)&Vs[(t * 32 + l31) * 64 + (((4 * tau + 2 * kc + hf) ^ swz) * 8)];
                    Ot[0][t] = __builtin_amdgcn_mfma_f32_32x32x16_bf16(va, pf0.v, Ot[0][t], 0, 0, 0);
                    Ot[1][t] = __builtin_amdgcn_mfma_f32_32x32x16_bf16(va, pf1.v, Ot[1][t], 0, 0, 0);
                }
            }
        }
        __syncthreads();
    }

    // epilogue: bf16 partial O^T + f32 partial l
    size_t pb = (size_t)kh * NROWS + (size_t)bh * SEQ;
#pragma unroll
    for (int j = 0; j < 2; ++j) {
        int q = qbase + j * 32 + l31;
        float lr = lp[j] + __shfl_xor(lp[j], 32);
        if (hf == 0) lpart[pb + q] = lr;
        size_t rowb = (pb + q) * HD;
#pragma unroll
        for (int t = 0; t < 3; ++t) {
#pragma unroll
            for (int g2 = 0; g2 < 4; ++g2) {
                int d0 = t * 32 + 8 * g2 + 4 * hf;
                uint2 val;
                val.x = pk2(Ot[j][t][g2 * 4 + 0], Ot[j][t][g2 * 4 + 1]);
                val.y = pk2(Ot[j][t][g2 * 4 + 2], Ot[j][t][g2 * 4 + 3]);
                *(uint2*)&part[rowb + d0] = val;
            }
        }
    }
}

// combine: ao[b][n][h*96+d] = (sum_kh part_kh) * SCALING / (sum_kh l_kh)
__global__ __launch_bounds__(256) void combine_kernel(const u16* __restrict__ part,
                                                      const float* __restrict__ lpart,
                                                      u16* __restrict__ ao) {
    int idx = blockIdx.x * 256 + threadIdx.x;       // NROWS*12 threads
    int row = idx / 12, ch = idx % 12;
    float l = 0.f;
#pragma unroll
    for (int k = 0; k < KSPLIT; ++k) l += lpart[(size_t)k * NROWS + row];
    float sc = SCALING / l;
    float acc[8] = {};
#pragma unroll
    for (int k = 0; k < KSPLIT; ++k) {
        uint4 pv = *(const uint4*)&part[((size_t)k * NROWS + row) * HD + ch * 8];
        const u16* a = (const u16*)&pv;
#pragma unroll
        for (int i = 0; i < 8; ++i) acc[i] += bf2f(a[i]);
    }
    uint4 o;
    u32* ou = (u32*)&o;
#pragma unroll
    for (int i = 0; i < 4; ++i)
        ou[i] = pk2(acc[2 * i] * sc, acc[2 * i + 1] * sc);
    int bh = row >> 11, n = row & 2047;
    int b = bh >> 3, h = bh & 7;
    *(uint4*)&ao[((size_t)(b * SEQ + n)) * EMB + h * HD + ch * 8] = o;
}

// ---------------- launch ----------------

extern "C" void kernel_launch(void* const* d_in, const int* in_sizes, int n_in,
                              void* d_out, int out_size, void* d_ws, size_t ws_size,
                              hipStream_t stream) {
    const float* x     = (const float*)d_in[0];
    const float* Wqkv  = (const float*)d_in[1];
    const float* bqkv  = (const float*)d_in[2];
    const float* Wproj = (const float*)d_in[3];
    const float* bproj = (const float*)d_in[4];
    float* out = (float*)d_out;

    // workspace: persistent buffers, then a union region (xb/wqkT/wvr alias partb:
    // xb & weights are dead once attn starts; partb is written by attn).
    char* p = (char*)d_ws;
    u16*   qb    = (u16*)p;  p += (size_t)NROWS * HD * 2;          // 12.6 MB
    u16*   kg    = (u16*)p;  p += (size_t)NROWS * 128 * 2;         // 16.8 MB
    u16*   vt    = (u16*)p;  p += (size_t)NROWS * HD * 2;          // 12.6 MB
    u16*   ao    = (u16*)p;  p += (size_t)MTOK * EMB * 2;          // 12.6 MB
    u16*   wpt   = (u16*)p;  p += (size_t)EMB * EMB * 2;           // 1.2 MB
    float* lpart = (float*)p; p += (size_t)KSPLIT * NROWS * 4;     // 1.05 MB
    char*  U     = p;                                              // union region
    u16*   xb    = (u16*)U;
    u16*   wqkT  = (u16*)(U + (size_t)MTOK * EMB * 2);
    u16*   wvr   = (u16*)(U + (size_t)MTOK * EMB * 2 + (size_t)1536 * EMB * 2);
    u16*   partb = (u16*)U;                                        // 50.3 MB

    prep_kernel<<<3648, 256, 0, stream>>>(x, Wqkv, Wproj, xb, wqkT, wvr, wpt);
    gemm_qk_kernel<<<dim3(1536 / 128, MTOK / 128), 256, 0, stream>>>(xb, wqkT, bqkv, qb, kg);
    gemm_v_kernel<<<dim3(MTOK / 64, EMB / 128), 256, 0, stream>>>(wvr, xb, bqkv, vt);
    attn_kernel<<<8 * 32 * KSPLIT, 256, 0, stream>>>(qb, kg, vt, partb, lpart);
    combine_kernel<<<NROWS * 12 / 256, 256, 0, stream>>>(partb, lpart, ao);
    gemm_proj_kernel<<<dim3(EMB / 64, MTOK / 128), 256, 0, stream>>>(ao, wpt, bproj, out);
}